// Round 1
// 1363.485 us; speedup vs baseline: 1.0169x; 1.0169x over previous
//
#include <hip/hip_runtime.h>

// B=4, H=16, S=2048, D=64. fp32 in; out = [context (B,H,S,D) | attn (B,H,S,S)] fp32.
// Two-pass strategy:
//   Pass 1 (prep, BW-bound ~40us): Q*(1/8), K -> bf16 row-major in ws; V -> bf16
//     TRANSPOSED [bh][d][s] in ws. Removes all fp32->bf16 VALU + V-transpose from hot loop.
//   Pass 2 (attn): per block 128 q-rows, 32 iters of 64 keys.
//     K / V^T tiles staged via global_load_lds dwordx4 (zero VALU staging),
//     double-buffered, prefetch issued right after the single per-iter barrier
//     so the vmcnt(0) drain at the next barrier lands after a full compute phase.
//     LDS XOR-swizzle (byte ^= (row&7)<<4) applied on BOTH sides: inverse-swizzled
//     global source addr (linear LDS dest, global_load_lds requirement) + swizzled
//     ds_read_b128 -> conflict-free.
//     QK^T: S^T = K * Qscaled^T -> float4 attn stores (4 consecutive keys/lane).
//     PV with swapped operands: ctx^T = V^T * P^T (A/B frags have identical lane
//     maps) -> float4 ctx stores in epilogue. P->bf16 via v_cvt_pk_bf16_f32.

typedef __attribute__((ext_vector_type(4))) float f32x4;
typedef __attribute__((ext_vector_type(8))) short bf16x8;
typedef __attribute__((ext_vector_type(2))) unsigned u32x2;

#define S_LEN 2048
#define D_HEAD 64
#define NELEM 8388608  // 64 heads * 2048 * 64

__device__ __forceinline__ unsigned pkbf(float a, float b) {
  unsigned r;
  asm("v_cvt_pk_bf16_f32 %0, %1, %2" : "=v"(r) : "v"(a), "v"(b));  // lo=a, hi=b, RNE
  return r;
}

__device__ __forceinline__ bf16x8 pack8(f32x4 a, f32x4 b) {
  union { unsigned u[4]; bf16x8 v; } r;
  r.u[0] = pkbf(a[0], a[1]); r.u[1] = pkbf(a[2], a[3]);
  r.u[2] = pkbf(b[0], b[1]); r.u[3] = pkbf(b[2], b[3]);
  return r.v;
}

__device__ __forceinline__ void gload16(const void* g, void* l) {
  __builtin_amdgcn_global_load_lds(
      (const __attribute__((address_space(1))) unsigned int*)g,
      (__attribute__((address_space(3))) unsigned int*)l, 16, 0, 0);
}

// ---------------- Pass 1: convert + transpose ----------------
__global__ __launch_bounds__(256) void sdpa_prep_kernel(
    const float* __restrict__ Q, const float* __restrict__ K,
    const float* __restrict__ V, short* __restrict__ Qb,
    short* __restrict__ Kb, short* __restrict__ Vt) {
  const int tid = threadIdx.x;
  if (blockIdx.x < 2048) {
    // Q (scaled by 1/8) and K -> bf16 row-major, 8 elems per thread-iter
    const size_t N8 = NELEM / 8;
    for (size_t i = (size_t)blockIdx.x * 256 + tid; i < 2 * N8; i += (size_t)2048 * 256) {
      const float* src; short* dst; float sc; size_t j;
      if (i < N8) { src = Q; dst = Qb; sc = 0.125f; j = i; }
      else        { src = K; dst = Kb; sc = 1.0f;   j = i - N8; }
      const f32x4* p = (const f32x4*)(src + j * 8);
      f32x4 a = p[0] * sc, b = p[1] * sc;
      *(bf16x8*)(dst + j * 8) = pack8(a, b);
    }
  } else {
    // V [bh][s][d] fp32 -> Vt [bh][d][s] bf16, 64x64 tiles through LDS
    __shared__ short tile[64 * 72];
    const int bid = blockIdx.x - 2048;
    const int st = bid & 31, bh = bid >> 5;
    const float* Vh = V + ((size_t)bh * S_LEN + st * 64) * D_HEAD;
    const int r = tid >> 2, c0 = (tid & 3) * 16;
    const f32x4* p = (const f32x4*)(Vh + r * D_HEAD + c0);
    f32x4 a = p[0], b = p[1], c = p[2], d = p[3];
    *(bf16x8*)&tile[r * 72 + c0] = pack8(a, b);
    *(bf16x8*)&tile[r * 72 + c0 + 8] = pack8(c, d);
    __syncthreads();
    union { short s[8]; bf16x8 v; } o0, o1;
#pragma unroll
    for (int j = 0; j < 8; ++j) o0.s[j] = tile[(c0 + j) * 72 + r];
#pragma unroll
    for (int j = 0; j < 8; ++j) o1.s[j] = tile[(c0 + 8 + j) * 72 + r];
    short* out = Vt + ((size_t)bh * D_HEAD + r) * S_LEN + st * 64 + c0;
    *(bf16x8*)out = o0.v;
    *(bf16x8*)(out + 8) = o1.v;
  }
}

// ---------------- Pass 2: attention ----------------
__global__ __launch_bounds__(256, 3) void ScaledDotProductAttention_40166534152796_kernel(
    const short* __restrict__ Qb, const short* __restrict__ Kb,
    const short* __restrict__ Vt, float* __restrict__ ctx,
    float* __restrict__ attn) {
  // LDS: [0,16KB) K tiles dbuf [key][d], [16KB,32KB) V^T tiles dbuf [d][key],
  //      [32KB,48KB) Pb [128 q][64 key]. All bf16, 128B rows, XOR-swizzled.
  __shared__ __align__(128) char lds[49152];
  char* ldsK = lds;
  char* ldsV = lds + 16384;
  char* ldsP = lds + 32768;

  const int tid = threadIdx.x;
  const int wave = tid >> 6;
  const int lane = tid & 63;
  const int t = lane & 15;
  const int quad = lane >> 4;
  const int sw = (t & 7) << 4;  // read-side XOR swizzle (rows below are == t mod 8-group)

  const int qblk = blockIdx.x;  // 0..15
  const int bh = blockIdx.y;    // 0..63

  const short* Qh = Qb + (size_t)bh * (S_LEN * D_HEAD);
  const char* Kh = (const char*)(Kb + (size_t)bh * (S_LEN * D_HEAD));
  const char* Vh = (const char*)(Vt + (size_t)bh * (S_LEN * D_HEAD));
  float* ctxh = ctx + (size_t)bh * (S_LEN * D_HEAD);
  float* attnh = attn + (size_t)bh * ((size_t)S_LEN * S_LEN);

  // Q B-fragments (pre-scaled bf16): lane t -> q, elem j -> d = s*32+quad*8+j
  bf16x8 qfrag[2][2];
#pragma unroll
  for (int qc = 0; qc < 2; ++qc)
#pragma unroll
    for (int s = 0; s < 2; ++s) {
      const int qrow = qblk * 128 + wave * 32 + qc * 16 + t;
      qfrag[qc][s] = *(const bf16x8*)(Qh + qrow * D_HEAD + s * 32 + quad * 8);
    }

  // global_load_lds: dest = uniform base + lane*16 (linear). Pre-apply the
  // INVERSE swizzle (same XOR, involution) to the per-lane global source.
  int koff[2], voff[2];
#pragma unroll
  for (int i = 0; i < 2; ++i) {
    const int o = wave * 2048 + i * 1024 + lane * 16;  // linear byte offset in 8KB tile
    const int r = o >> 7;                               // tile row (key for K, d for V^T)
    const int bs = (o & 127) ^ ((r & 7) << 4);          // swizzled byte-in-row
    koff[i] = r * 128 + bs;    // K head: row stride 128B
    voff[i] = r * 4096 + bs;   // V^T head: row stride S*2 = 4096B
  }

  f32x4 accT[4][2];  // ctx^T accumulators: [d-tile c][q-tile r]
#pragma unroll
  for (int c = 0; c < 4; ++c)
#pragma unroll
    for (int r = 0; r < 2; ++r) accT[c][r] = (f32x4)(0.0f);

  // prologue: stage tile 0 into buf 0
#pragma unroll
  for (int i = 0; i < 2; ++i) {
    gload16(Kh + koff[i], ldsK + wave * 2048 + i * 1024);
    gload16(Vh + voff[i], ldsV + wave * 2048 + i * 1024);
  }

  for (int kt = 0; kt < 32; ++kt) {
    const int bsel = (kt & 1) * 8192;
    __syncthreads();  // vmcnt(0) drain: tile kt staged; prev iter's reads done

    if (kt < 31) {  // issue next tile's loads now; latency hides under compute
      const int nsel = ((kt + 1) & 1) * 8192;
      const size_t kg = (size_t)(kt + 1) * 8192;
      const size_t vg = (size_t)(kt + 1) * 128;
#pragma unroll
      for (int i = 0; i < 2; ++i) {
        gload16(Kh + kg + koff[i], ldsK + nsel + wave * 2048 + i * 1024);
        gload16(Vh + vg + voff[i], ldsV + nsel + wave * 2048 + i * 1024);
      }
    }

    // ---- QK^T: S^T tile [64 key x 32 q] per wave ----
    const char* Kt_ = ldsK + bsel;
    bf16x8 afr[4][2];
#pragma unroll
    for (int kr = 0; kr < 4; ++kr)
#pragma unroll
      for (int s = 0; s < 2; ++s)
        afr[kr][s] = *(const bf16x8*)(Kt_ + (kr * 16 + t) * 128 + ((s * 64 + quad * 16) ^ sw));

    f32x4 sa[4][2];
#pragma unroll
    for (int kr = 0; kr < 4; ++kr)
#pragma unroll
      for (int qc = 0; qc < 2; ++qc) sa[kr][qc] = (f32x4)(0.0f);

    __builtin_amdgcn_s_setprio(1);
#pragma unroll
    for (int s = 0; s < 2; ++s)
#pragma unroll
      for (int kr = 0; kr < 4; ++kr)
#pragma unroll
        for (int qc = 0; qc < 2; ++qc)
          sa[kr][qc] = __builtin_amdgcn_mfma_f32_16x16x32_bf16(
              afr[kr][s], qfrag[qc][s], sa[kr][qc], 0, 0, 0);
    __builtin_amdgcn_s_setprio(0);

    // ---- relu -> attn (nontemporal float4) + Pb (cvt_pk, 8B swizzled) ----
#pragma unroll
    for (int kr = 0; kr < 4; ++kr)
#pragma unroll
      for (int qc = 0; qc < 2; ++qc) {
        f32x4 v = sa[kr][qc];
#pragma unroll
        for (int i = 0; i < 4; ++i) v[i] = fmaxf(v[i], 0.0f);
        const int qg = qblk * 128 + wave * 32 + qc * 16 + t;
        __builtin_nontemporal_store(
            v, (f32x4*)(attnh + (size_t)qg * S_LEN + kt * 64 + kr * 16 + quad * 4));
        u32x2 pw;
        pw[0] = pkbf(v[0], v[1]);
        pw[1] = pkbf(v[2], v[3]);
        *(u32x2*)(ldsP + (wave * 32 + qc * 16 + t) * 128 + ((kr * 32 + quad * 8) ^ sw)) = pw;
      }

    // ---- PV swapped: accT[c][r] += V^T_frag(c) * P^T_frag(r)  (= ctx^T) ----
    const char* Vt_ = ldsV + bsel;
    __builtin_amdgcn_s_setprio(1);
#pragma unroll
    for (int s2 = 0; s2 < 2; ++s2) {
      bf16x8 vb[4], pa[2];
#pragma unroll
      for (int c = 0; c < 4; ++c)
        vb[c] = *(const bf16x8*)(Vt_ + (c * 16 + t) * 128 + ((s2 * 64 + quad * 16) ^ sw));
#pragma unroll
      for (int r = 0; r < 2; ++r)
        pa[r] = *(const bf16x8*)(ldsP + (wave * 32 + r * 16 + t) * 128 +
                                 ((s2 * 64 + quad * 16) ^ sw));
#pragma unroll
      for (int c = 0; c < 4; ++c)
#pragma unroll
        for (int r = 0; r < 2; ++r)
          accT[c][r] = __builtin_amdgcn_mfma_f32_16x16x32_bf16(
              vb[c], pa[r], accT[c][r], 0, 0, 0);
    }
    __builtin_amdgcn_s_setprio(0);
  }

  // ---- ctx store: C^T layout -> lane holds 4 consecutive d for fixed q ----
#pragma unroll
  for (int r = 0; r < 2; ++r)
#pragma unroll
    for (int c = 0; c < 4; ++c) {
      const int qg = qblk * 128 + wave * 32 + r * 16 + t;
      *(f32x4*)(ctxh + (size_t)qg * D_HEAD + c * 16 + quad * 4) = accT[c][r];
    }
}

extern "C" void kernel_launch(void* const* d_in, const int* in_sizes, int n_in,
                              void* d_out, int out_size, void* d_ws, size_t ws_size,
                              hipStream_t stream) {
  const float* Q = (const float*)d_in[0];
  const float* K = (const float*)d_in[1];
  const float* V = (const float*)d_in[2];
  float* ctx = (float*)d_out;
  float* attn = (float*)d_out + (size_t)NELEM;  // context first, then attn

  short* Qb = (short*)d_ws;          // 16.78 MB bf16 Q * (1/8), row-major
  short* Kb = Qb + (size_t)NELEM;    // 16.78 MB bf16 K, row-major
  short* Vt = Kb + (size_t)NELEM;    // 16.78 MB bf16 V^T [bh][d][s]

  sdpa_prep_kernel<<<dim3(4096, 1, 1), dim3(256, 1, 1), 0, stream>>>(Q, K, V, Qb, Kb, Vt);
  ScaledDotProductAttention_40166534152796_kernel<<<dim3(16, 64, 1), dim3(256, 1, 1), 0,
                                                    stream>>>(Qb, Kb, Vt, ctx, attn);
}